// Round 12
// baseline (320.306 us; speedup 1.0000x reference)
//
#include <hip/hip_runtime.h>
#include <math.h>

#define NH 8
#define HD 64
#define NSEQ 1024
#define DMODEL 512
#define F3 1536
#define NTOK 16384
#define BH 128    // (B*T)*NH = 16*8
#define KVP 72    // attn K/V LDS pitch (bf16)
#define TP 136    // qkv epilogue transpose pitch (bf16)
#define QSCALE 0.1803368867f  // 0.125 * log2(e), folded into q; p = exp2(s')

typedef __attribute__((ext_vector_type(8))) short bf16x8;
typedef __attribute__((ext_vector_type(4))) float f32x4;
typedef __attribute__((ext_vector_type(16))) float f32x16;
typedef __attribute__((ext_vector_type(4))) unsigned int u32x4;
#define MFMA16(a, b, c) __builtin_amdgcn_mfma_f32_16x16x32_bf16(a, b, c, 0, 0, 0)
#define MFMA32(a, b, c) __builtin_amdgcn_mfma_f32_32x32x16_bf16(a, b, c, 0, 0, 0)

__device__ __forceinline__ float freq_of(int j) {
    return 3.14159265358979323846f * (1.0f + (float)j * (127.0f / 15.0f));
}
__device__ __forceinline__ unsigned short bf16_rtn(float x) {
    unsigned u = __builtin_bit_cast(unsigned, x);
    return (unsigned short)((u + 0x7FFF + ((u >> 16) & 1)) >> 16);  // round-nearest-even
}
// 2-bit LDS swizzle key for row r (permutes 16-B col-groups within a 64-B row)
__device__ __forceinline__ int swz(int r) { return (r & 3) ^ ((r >> 2) & 3); }

// ---------------- Kernel 0: fp32 -> bf16 RTN, both weight tensors ----------------
__global__ __launch_bounds__(256) void cvt2_kernel(
        const float* __restrict__ wq, unsigned short* __restrict__ wq_bf,
        const float* __restrict__ wo, unsigned short* __restrict__ wo_bf) {
    const int b = blockIdx.x;
    const float* src;
    unsigned short* dst;
    int i;
    if (b < F3 * DMODEL / 1024) { src = wq; dst = wq_bf; i = b * 256 + threadIdx.x; }
    else { src = wo; dst = wo_bf; i = (b - F3 * DMODEL / 1024) * 256 + threadIdx.x; }
    const float4 v = ((const float4*)src)[i];
    ((ushort4*)dst)[i] = make_ushort4(bf16_rtn(v.x), bf16_rtn(v.y),
                                      bf16_rtn(v.z), bf16_rtn(v.w));
}

// ---- register-staged pipelined GEMM core, SINGLE reg set, load-one-iter-ahead ----
// Schedule: barrier -> compute(kt) -> store(kt+1) -> load(kt+2). The store's
// vmcnt wait covers loads issued a FULL iteration earlier (store+barrier+compute
// ~900 cyc) instead of same-phase (~300 cyc). Zero extra registers (rounds
// 10/11 showed multi-set staging through lambdas spills on this compiler).
template<int PLANES, int NREP>
__device__ __forceinline__ void gemm_reg_pipe(
        const unsigned short* __restrict__ a_hi, const unsigned short* __restrict__ a_lo,
        const unsigned short* __restrict__ b_bf,
        char* lds, int m0, int f0, int t, f32x4 (&acc)[NREP][4][4]) {
    const int w = t >> 6, lane = t & 63, l15 = lane & 15, quad = lane >> 4;
    const int mw = (w & 1) * 64, nw = (w >> 1) * 64;
    const int APL = PLANES - 1;           // A planes
    const int NPL = APL + NREP;           // total planes
    const int STAGE = NPL * 4096;         // elements per stage
    const int r = t >> 1;                 // 0..127: row this thread stages
    const int g0 = (t & 1) * 2;           // first of two 16-B col-groups

    uint4 regs[NPL][2];
    auto load_regs = [&](int kt) {
        const int k0 = kt * 32;
        #pragma unroll
        for (int p = 0; p < NPL; p++) {
            const unsigned short* src = (p < APL) ? (p == 0 ? a_hi : a_lo) : b_bf;
            const int row0 = (p < APL) ? m0 : (f0 + (p - APL) * 128);
            const unsigned short* g = src + (size_t)(row0 + r) * DMODEL + k0 + g0 * 8;
            regs[p][0] = *(const uint4*)g;
            regs[p][1] = *(const uint4*)(g + 8);
        }
    };
    auto store_lds = [&](int stage) {
        unsigned short* S = (unsigned short*)lds + stage * STAGE;
        const int s0 = ((g0 ^ swz(r))) * 8;
        const int s1 = (((g0 + 1) ^ swz(r))) * 8;
        #pragma unroll
        for (int p = 0; p < NPL; p++) {
            unsigned short* Sp = S + p * 4096 + r * 32;
            *(uint4*)&Sp[s0] = regs[p][0];
            *(uint4*)&Sp[s1] = regs[p][1];
        }
    };

    load_regs(0);
    store_lds(0);
    load_regs(1);                         // in flight across barrier + compute(0)
    for (int kt = 0; kt < 16; kt++) {
        __syncthreads();                  // stage (kt&1) visible to all waves
        const unsigned short* S = (const unsigned short*)lds + (kt & 1) * STAGE;
        bf16x8 ah[4], al[4];
        #pragma unroll
        for (int mt = 0; mt < 4; mt++) {
            const int rr = mw + mt * 16 + l15;
            const int off = rr * 32 + (quad ^ swz(rr)) * 8;
            ah[mt] = *(const bf16x8*)&S[off];
            if (APL == 2) al[mt] = *(const bf16x8*)&S[4096 + off];
        }
        #pragma unroll
        for (int nr = 0; nr < NREP; nr++) {
            bf16x8 bb[4];
            #pragma unroll
            for (int nt = 0; nt < 4; nt++) {
                const int rr = nw + nt * 16 + l15;
                bb[nt] = *(const bf16x8*)&S[(APL + nr) * 4096 + rr * 32
                                            + (quad ^ swz(rr)) * 8];
            }
            #pragma unroll
            for (int mt = 0; mt < 4; mt++)
                #pragma unroll
                for (int nt = 0; nt < 4; nt++) {
                    acc[nr][mt][nt] = MFMA16(ah[mt], bb[nt], acc[nr][mt][nt]);
                    if (APL == 2) acc[nr][mt][nt] = MFMA16(al[mt], bb[nt], acc[nr][mt][nt]);
                }
        }
        if (kt < 15) store_lds((kt + 1) & 1);  // regs loaded a full iter ago
        if (kt < 14) load_regs(kt + 2);        // issue next; lands before next store
    }
    __syncthreads();                      // LDS free for epilogue reuse
}

// ---- qkv pipe: fp32 A -> SINGLE bf16 RTN plane, single-set, load-ahead ----
__device__ __forceinline__ void gemm_pipe_qkv(
        const float* __restrict__ x, const unsigned short* __restrict__ b_bf,
        char* lds, int m0, int f0, int t, f32x4 (&acc)[2][4][4]) {
    const int w = t >> 6, lane = t & 63, l15 = lane & 15, quad = lane >> 4;
    const int mw = (w & 1) * 64, nw = (w >> 1) * 64;
    const int STAGE = 3 * 4096;           // planes: 0=A 1=B(f0) 2=B(f0+128)
    const int r = t >> 1;
    const int g0 = (t & 1) * 2;

    float4 af[4];                         // 16 fp32 of A row r, cols k0+g0*8..+16
    uint4 bregs[2][2];
    auto load_regs = [&](int kt) {
        const int k0 = kt * 32;
        const float* gA = x + (size_t)(m0 + r) * DMODEL + k0 + g0 * 8;
        #pragma unroll
        for (int i = 0; i < 4; i++) af[i] = ((const float4*)gA)[i];
        #pragma unroll
        for (int p = 0; p < 2; p++) {
            const unsigned short* g =
                b_bf + (size_t)(f0 + p * 128 + r) * DMODEL + k0 + g0 * 8;
            bregs[p][0] = *(const uint4*)g;
            bregs[p][1] = *(const uint4*)(g + 8);
        }
    };
    auto store_lds = [&](int stage) {
        unsigned short* S = (unsigned short*)lds + stage * STAGE;
        const int s0 = ((g0 ^ swz(r))) * 8;
        const int s1 = (((g0 + 1) ^ swz(r))) * 8;
        // pack 8 floats -> one uint4 of RTN bf16
        auto cvt8 = [](const float4 a, const float4 b) {
            const float f[8] = {a.x, a.y, a.z, a.w, b.x, b.y, b.z, b.w};
            unsigned hw[4];
            #pragma unroll
            for (int j = 0; j < 4; j++)
                hw[j] = (unsigned)bf16_rtn(f[2 * j])
                      | ((unsigned)bf16_rtn(f[2 * j + 1]) << 16);
            return make_uint4(hw[0], hw[1], hw[2], hw[3]);
        };
        unsigned short* Sa = S + r * 32;
        *(uint4*)&Sa[s0] = cvt8(af[0], af[1]);
        *(uint4*)&Sa[s1] = cvt8(af[2], af[3]);
        #pragma unroll
        for (int p = 0; p < 2; p++) {
            unsigned short* Sp = S + (1 + p) * 4096 + r * 32;
            *(uint4*)&Sp[s0] = bregs[p][0];
            *(uint4*)&Sp[s1] = bregs[p][1];
        }
    };

    load_regs(0);
    store_lds(0);
    load_regs(1);                         // in flight across barrier + compute(0)
    for (int kt = 0; kt < 16; kt++) {
        __syncthreads();
        const unsigned short* S = (const unsigned short*)lds + (kt & 1) * STAGE;
        bf16x8 ah[4];
        #pragma unroll
        for (int mt = 0; mt < 4; mt++) {
            const int rr = mw + mt * 16 + l15;
            ah[mt] = *(const bf16x8*)&S[rr * 32 + (quad ^ swz(rr)) * 8];
        }
        #pragma unroll
        for (int nr = 0; nr < 2; nr++) {
            bf16x8 bb[4];
            #pragma unroll
            for (int nt = 0; nt < 4; nt++) {
                const int rr = nw + nt * 16 + l15;
                bb[nt] = *(const bf16x8*)&S[(1 + nr) * 4096 + rr * 32
                                            + (quad ^ swz(rr)) * 8];
            }
            #pragma unroll
            for (int mt = 0; mt < 4; mt++)
                #pragma unroll
                for (int nt = 0; nt < 4; nt++)
                    acc[nr][mt][nt] = MFMA16(ah[mt], bb[nt], acc[nr][mt][nt]);
        }
        if (kt < 15) store_lds((kt + 1) & 1);  // regs loaded a full iter ago
        if (kt < 14) load_regs(kt + 2);
    }
    __syncthreads();
}

// ---------------- Kernel 1: QKV GEMM + RoPE (128x256 tile, single-plane A) ----
__global__ __launch_bounds__(256, 3) void qkv_mfma_kernel(
        const float* __restrict__ x, const unsigned short* __restrict__ wq_bf,
        unsigned short* __restrict__ q_bf, unsigned short* __restrict__ k_bf,
        unsigned short* __restrict__ v_th) {
    __shared__ __align__(16) char lds[49152 + 4608];   // 2x24KB stages (+T alias) + tables
    unsigned short* T = (unsigned short*)lds;          // 128 x TP transpose buffer
    float* t_cy = (float*)(lds + 49152);               // [4][16]
    float* t_sy = t_cy + 64;
    float* t_cx = t_sy + 64;                           // [32][16]
    float* t_sx = t_cx + 512;

    const int m0 = blockIdx.x * 128;
    const int f0 = blockIdx.y * 256;
    const int t = threadIdx.x;
    const int w = t >> 6, lane = t & 63, l15 = lane & 15, quad = lane >> 4;
    const int mw = (w & 1) * 64, nw = (w >> 1) * 64;
    const int sel = f0 >> 9;                // 0=q,1=k,2=v (same for both subtiles)
    const int bt = m0 >> 10;
    const int n0 = m0 & 1023;

    if (sel != 2) {
        for (int idx = t; idx < 576; idx += 256) {
            if (idx < 64) {
                const int yi = idx >> 4, j = idx & 15;
                const float pos = -1.0f + (float)((n0 >> 5) + yi) * (2.0f / 31.0f);
                float sv, cv; sincosf(pos * freq_of(j), &sv, &cv);
                t_sy[idx] = sv; t_cy[idx] = cv;
            } else {
                const int k2 = idx - 64, xi = k2 >> 4, j = k2 & 15;
                const float pos = -1.0f + (float)xi * (2.0f / 31.0f);
                float sv, cv; sincosf(pos * freq_of(j), &sv, &cv);
                t_sx[k2] = sv; t_cx[k2] = cv;
            }
        }
    }
    __syncthreads();

    f32x4 acc[2][4][4];
    #pragma unroll
    for (int nr = 0; nr < 2; nr++)
        #pragma unroll
        for (int mt = 0; mt < 4; mt++)
            #pragma unroll
            for (int nt = 0; nt < 4; nt++) acc[nr][mt][nt] = (f32x4){0.f, 0.f, 0.f, 0.f};

    gemm_pipe_qkv(x, wq_bf, lds, m0, f0, t, acc);

    #pragma unroll
    for (int nr = 0; nr < 2; nr++) {
        const int fs = f0 + nr * 128;
        if (sel != 2) {
            const float post = (sel == 0) ? QSCALE : 1.0f;
            #pragma unroll
            for (int mt = 0; mt < 4; mt++)
                #pragma unroll
                for (int nt = 0; nt < 4; nt++)
                    #pragma unroll
                    for (int rr = 0; rr < 4; rr++) {
                        const int ml = mw + mt * 16 + quad * 4 + rr;
                        const int dd = (nw + nt * 16 + l15) & 63;
                        const int j0 = (dd & 31) >> 1;
                        float c, s;
                        if (dd < 32) { c = t_cy[(ml >> 5) * 16 + j0]; s = t_sy[(ml >> 5) * 16 + j0]; }
                        else         { c = t_cx[(ml & 31) * 16 + j0]; s = t_sx[(ml & 31) * 16 + j0]; }
                        const float v = acc[nr][mt][nt][rr];
                        const float pv = __shfl_xor(v, 1);
                        acc[nr][mt][nt][rr] =
                            ((l15 & 1) ? (v * c + pv * s) : (v * c - pv * s)) * post;
                    }
        }

        if (sel == 2) {
            #pragma unroll
            for (int mt = 0; mt < 4; mt++)
                #pragma unroll
                for (int nt = 0; nt < 4; nt++) {
                    const int fl = nw + nt * 16 + l15;
                    const int mlb = mw + mt * 16 + quad * 4;
                    ushort4 pk = make_ushort4(
                        bf16_rtn(acc[nr][mt][nt][0]), bf16_rtn(acc[nr][mt][nt][1]),
                        bf16_rtn(acc[nr][mt][nt][2]), bf16_rtn(acc[nr][mt][nt][3]));
                    *(ushort4*)&T[fl * TP + mlb] = pk;
                }
        } else {
            #pragma unroll
            for (int mt = 0; mt < 4; mt++)
                #pragma unroll
                for (int nt = 0; nt < 4; nt++)
                    #pragma unroll
                    for (int rr = 0; rr < 4; rr++) {
                        const int ml = mw + mt * 16 + quad * 4 + rr;
                        const int fl = nw + nt * 16 + l15;
                        T[ml * TP + fl] = bf16_rtn(acc[nr][mt][nt][rr]);
                    }
        }
        __syncthreads();
        if (sel == 2) {
            #pragma unroll
            for (int p = 0; p < 8; p++) {
                const int idx = p * 256 + t;
                const int fl = idx >> 4, g8 = (idx & 15) * 8;
                const int head = ((fs + fl) >> 6) & 7;
                *(uint4*)(v_th + ((size_t)(bt * NH + head) * HD + ((fs + fl) & 63)) * NSEQ
                          + n0 + g8) = *(const uint4*)&T[fl * TP + g8];
            }
        } else {
            unsigned short* dst = (sel == 0) ? q_bf : k_bf;
            #pragma unroll
            for (int p = 0; p < 8; p++) {
                const int idx = p * 256 + t;
                const int ml = idx >> 4, g8 = (idx & 15) * 8;
                const int head = ((fs + g8) >> 6) & 7;
                *(uint4*)(dst + ((size_t)(bt * NH + head) * NSEQ + n0 + ml) * HD
                          + ((fs + g8) & 63)) = *(const uint4*)&T[ml * TP + g8];
            }
        }
        __syncthreads();
    }
}

// ---------------- Kernel 2: flash attention, 8 waves x 32 q-rows, QBLK=256 ----
__global__ __launch_bounds__(512, 2) void attn_kernel(
        const unsigned short* __restrict__ q_bf, const unsigned short* __restrict__ k_bf,
        const unsigned short* __restrict__ v_th,
        unsigned short* __restrict__ o_bf) {
    __shared__ unsigned short Ks[2][64 * KVP];  // K tile [n][d], double-buffered
    __shared__ unsigned short Vs[2][64 * KVP];  // V^T tile [d][n], double-buffered
    __shared__ float Lsh[256];                  // per-row 1/l broadcast

    const int bh = blockIdx.x;     // fastest dim -> XCD = bh & 7 for all 4 qt blocks
    const int qt = blockIdx.y;     // 0..3
    const int t = threadIdx.x;     // 0..511
    const int w = t >> 6;          // 0..7: wave owns 32 q-rows
    const int lane = t & 63;
    const int l31 = lane & 31;
    const int hi = lane >> 5;

    const size_t bh_nd = (size_t)bh * NSEQ * HD;
    const size_t bh_dn = (size_t)bh * HD * NSEQ;

    // Q B-fragments: qrow = qt*256 + w*32 + l31
    bf16x8 qfB[4];
    {
        const size_t rbase =
            bh_nd + (size_t)(qt * 256 + w * 32 + l31) * HD + hi * 8;
        #pragma unroll
        for (int ds = 0; ds < 4; ds++)
            qfB[ds] = *(const bf16x8*)(q_bf + rbase + ds * 16);
    }

    // staging: 512 threads x 1 uint4 each for K and V (64x64 tile each)
    const int sr = t >> 3, soff = (t & 7) * 8;
    uint4 kr, vr;
    auto load_kv = [&](int kt) {
        kr = *(const uint4*)(k_bf + bh_nd + (size_t)(kt * 64 + sr) * HD + soff);
        vr = *(const uint4*)(v_th + bh_dn + (size_t)sr * NSEQ + kt * 64 + soff);
    };
    auto store_kv = [&](int st) {
        *(uint4*)&Ks[st][sr * KVP + soff] = kr;
        *(uint4*)&Vs[st][sr * KVP + soff] = vr;
    };

    f32x16 o_acc[2], zero16;
    float l_sum = 0.f;
    #pragma unroll
    for (int i = 0; i < 16; i++) {
        o_acc[0][i] = 0.f; o_acc[1][i] = 0.f; zero16[i] = 0.f;
    }

    load_kv(0);
    store_kv(0);
    load_kv(1);                           // in flight across barrier + compute(0)
    for (int kt = 0; kt < 16; kt++) {
        __syncthreads();                  // stage (kt&1) visible
        const unsigned short* K = Ks[kt & 1];
        const unsigned short* V = Vs[kt & 1];

        #pragma unroll
        for (int nt2 = 0; nt2 < 2; nt2++) {
            bf16x8 kb[4];
            #pragma unroll
            for (int ds = 0; ds < 4; ds++)
                kb[ds] = *(const bf16x8*)&K[(nt2 * 32 + l31) * KVP + ds * 16 + hi * 8];

            // ---- S^T = K · Q^T (zero16-seeded) ----
            __builtin_amdgcn_s_setprio(1);
            f32x16 s = MFMA32(kb[0], qfB[0], zero16);
            #pragma unroll
            for (int ds = 1; ds < 4; ds++) s = MFMA32(kb[ds], qfB[ds], s);
            __builtin_amdgcn_s_setprio(0);

            // ---- p = exp2(s); accumulate l in-lane; pack pairs to bf16 ----
            unsigned wv[8];
            float pp[8];
            #pragma unroll
            for (int i = 0; i < 8; i++) {
                const float p0 = exp2f(s[2 * i]);
                const float p1 = exp2f(s[2 * i + 1]);
                pp[i] = p0 + p1;
                asm("v_cvt_pk_bf16_f32 %0, %1, %2" : "=v"(wv[i]) : "v"(p0), "v"(p1));
            }
            l_sum += ((pp[0] + pp[1]) + (pp[2] + pp[3]))
                   + ((pp[4] + pp[5]) + (pp[6] + pp[7]));

            // ---- exchange halves: vdst.hi <-> vsrc.lo (first operand = lower-k word)
            asm volatile("v_permlane32_swap_b32 %0, %1" : "+v"(wv[0]), "+v"(wv[2]));
            asm volatile("v_permlane32_swap_b32 %0, %1" : "+v"(wv[1]), "+v"(wv[3]));
            asm volatile("v_permlane32_swap_b32 %0, %1" : "+v"(wv[4]), "+v"(wv[6]));
            asm volatile("v_permlane32_swap_b32 %0, %1" : "+v"(wv[5]), "+v"(wv[7]));

            // ---- O += P·V (P entirely in registers) ----
            __builtin_amdgcn_s_setprio(1);
            #pragma unroll
            for (int k2 = 0; k2 < 2; k2++) {
                const u32x4 paw = {wv[k2 * 4 + 0], wv[k2 * 4 + 1],
                                   wv[k2 * 4 + 2], wv[k2 * 4 + 3]};
                const bf16x8 pa = __builtin_bit_cast(bf16x8, paw);
                #pragma unroll
                for (int dt = 0; dt < 2; dt++) {
                    const bf16x8 vb = *(const bf16x8*)&V[(dt * 32 + l31) * KVP
                                         + (nt2 * 2 + k2) * 16 + hi * 8];
                    o_acc[dt] = MFMA32(pa, vb, o_acc[dt]);
                }
            }
            __builtin_amdgcn_s_setprio(0);
        }
        if (kt < 15) store_kv((kt + 1) & 1);  // regs loaded a full iter ago
        if (kt < 14) load_kv(kt + 2);
    }

    // ---- combine row-sum halves; broadcast 1/l via LDS (intra-wave rows) ----
    l_sum += __shfl_xor(l_sum, 32);
    const float inv = 1.0f / l_sum;
    if (hi == 0) Lsh[w * 32 + l31] = inv;
    __syncthreads();                       // Lsh visible + Ks/Vs reads done

    // ---- epilogue: LDS bounce -> full-128B-line uint4 stores ----
    unsigned short* Osh = &Ks[0][0];       // 256 rows x KVP pitch = 18432 els (Ks+Vs)
    #pragma unroll
    for (int r = 0; r < 16; r++) {
        const int row32 = (r & 3) + 8 * (r >> 2) + 4 * hi;
        const float invr = Lsh[w * 32 + row32];
        const int row = w * 32 + row32;
        #pragma unroll
        for (int dt = 0; dt < 2; dt++)
            Osh[row * KVP + dt * 32 + l31] = bf16_rtn(o_acc[dt][r] * invr);
    }
    __syncthreads();
    const int btq = bh >> 3, head = bh & 7;
    #pragma unroll
    for (int p = 0; p < 4; p++) {
        const int idx = p * 512 + t;
        const int row = idx >> 3, g8 = (idx & 7) * 8;
        *(uint4*)(o_bf + ((size_t)(btq * NSEQ + qt * 256 + row)) * DMODEL
                  + head * HD + g8) = *(const uint4*)&Osh[row * KVP + g8];
    }
}

// ---------------- Kernel 3: output projection (128x256, NREP=2, load-ahead pipe) ----
__global__ __launch_bounds__(256, 2) void proj_mfma_kernel(
        const unsigned short* __restrict__ o_bf,
        const unsigned short* __restrict__ wo_bf,
        const float* __restrict__ b_out, float* __restrict__ out) {
    __shared__ __align__(16) char lds[49152];   // 2 x 24KB stages (3 planes)

    const int m0 = blockIdx.x * 128;
    const int f0 = blockIdx.y * 256;
    const int t = threadIdx.x;
    const int w = t >> 6, lane = t & 63, l15 = lane & 15, quad = lane >> 4;
    const int mw = (w & 1) * 64, nw = (w >> 1) * 64;

    f32x4 acc[2][4][4];
    #pragma unroll
    for (int nr = 0; nr < 2; nr++)
        #pragma unroll
        for (int mt = 0; mt < 4; mt++)
            #pragma unroll
            for (int nt = 0; nt < 4; nt++) acc[nr][mt][nt] = (f32x4){0.f, 0.f, 0.f, 0.f};

    gemm_reg_pipe<2, 2>(o_bf, o_bf, wo_bf, lds, m0, f0, t, acc);

    #pragma unroll
    for (int nr = 0; nr < 2; nr++) {
        const int fs = f0 + nr * 128;
        float bias_v[4];
        #pragma unroll
        for (int nt = 0; nt < 4; nt++) bias_v[nt] = b_out[fs + nw + nt * 16 + l15];
        #pragma unroll
        for (int mt = 0; mt < 4; mt++)
            #pragma unroll
            for (int nt = 0; nt < 4; nt++)
                #pragma unroll
                for (int rr = 0; rr < 4; rr++) {
                    const int m = m0 + mw + mt * 16 + quad * 4 + rr;
                    out[(size_t)m * DMODEL + fs + nw + nt * 16 + l15] =
                        acc[nr][mt][nt][rr] + bias_v[nt];
                }
    }
}

extern "C" void kernel_launch(void* const* d_in, const int* in_sizes, int n_in,
                              void* d_out, int out_size, void* d_ws, size_t ws_size,
                              hipStream_t stream) {
    const float* x  = (const float*)d_in[0];
    const float* wq = (const float*)d_in[1];
    const float* wo = (const float*)d_in[2];
    const float* bo = (const float*)d_in[3];
    float* out = (float*)d_out;

    const size_t per = (size_t)BH * NSEQ * HD;   // 8,388,608 elements
    unsigned short* o_bf = (unsigned short*)d_ws;
    unsigned short* q_bf = o_bf + per;
    unsigned short* k_bf = q_bf + per;
    unsigned short* v_th = k_bf + per;
    unsigned short* wq_bf = v_th + per;                   // 786,432 els
    unsigned short* wo_bf = wq_bf + (size_t)F3 * DMODEL;  // 262,144 els (~66 MiB total)

    cvt2_kernel<<<dim3((F3 * DMODEL + DMODEL * DMODEL) / 1024), 256, 0, stream>>>(
        wq, wq_bf, wo, wo_bf);
    qkv_mfma_kernel<<<dim3(NTOK / 128, F3 / 256), 256, 0, stream>>>(
        x, wq_bf, q_bf, k_bf, v_th);
    attn_kernel<<<dim3(BH, 4), 512, 0, stream>>>(
        q_bf, k_bf, v_th, o_bf);
    proj_mfma_kernel<<<dim3(NTOK / 128, DMODEL / 256), 256, 0, stream>>>(
        o_bf, wo_bf, bo, out);
}

// Round 13
// 204.177 us; speedup vs baseline: 1.5688x; 1.5688x over previous
//
#include <hip/hip_runtime.h>
#include <math.h>

#define NH 8
#define HD 64
#define NSEQ 1024
#define DMODEL 512
#define F3 1536
#define NTOK 16384
#define BH 128    // (B*T)*NH = 16*8
#define KVP 72    // attn K/V LDS pitch (bf16)
#define TP 136    // qkv epilogue transpose pitch (bf16)
#define QSCALE 0.1803368867f  // 0.125 * log2(e), folded into q; p = exp2(s')

typedef __attribute__((ext_vector_type(8))) short bf16x8;
typedef __attribute__((ext_vector_type(4))) float f32x4;
typedef __attribute__((ext_vector_type(16))) float f32x16;
typedef __attribute__((ext_vector_type(4))) unsigned int u32x4;
#define MFMA16(a, b, c) __builtin_amdgcn_mfma_f32_16x16x32_bf16(a, b, c, 0, 0, 0)
#define MFMA32(a, b, c) __builtin_amdgcn_mfma_f32_32x32x16_bf16(a, b, c, 0, 0, 0)

__device__ __forceinline__ float freq_of(int j) {
    return 3.14159265358979323846f * (1.0f + (float)j * (127.0f / 15.0f));
}
__device__ __forceinline__ unsigned short bf16_rtn(float x) {
    unsigned u = __builtin_bit_cast(unsigned, x);
    return (unsigned short)((u + 0x7FFF + ((u >> 16) & 1)) >> 16);  // round-nearest-even
}
// 2-bit LDS swizzle key for row r (permutes 16-B col-groups within a 64-B row)
__device__ __forceinline__ int swz(int r) { return (r & 3) ^ ((r >> 2) & 3); }

// ---------------- Kernel 0: fp32 -> bf16 RTN, both weight tensors ----------------
__global__ __launch_bounds__(256) void cvt2_kernel(
        const float* __restrict__ wq, unsigned short* __restrict__ wq_bf,
        const float* __restrict__ wo, unsigned short* __restrict__ wo_bf) {
    const int b = blockIdx.x;
    const float* src;
    unsigned short* dst;
    int i;
    if (b < F3 * DMODEL / 1024) { src = wq; dst = wq_bf; i = b * 256 + threadIdx.x; }
    else { src = wo; dst = wo_bf; i = (b - F3 * DMODEL / 1024) * 256 + threadIdx.x; }
    const float4 v = ((const float4*)src)[i];
    ((ushort4*)dst)[i] = make_ushort4(bf16_rtn(v.x), bf16_rtn(v.y),
                                      bf16_rtn(v.z), bf16_rtn(v.w));
}

// ---- register-staged pipelined GEMM core (round-9 schedule: spill-safe) ----
// Staging regs are loaded right after the barrier and consumed by store_lds at
// the END of the same iteration. Rounds 10/11/12 proved: ANY schedule whose
// staging live-range crosses a barrier + compute region spills to scratch on
// this compiler (WRITE_SIZE 390-594 MB). Do not deepen this pipeline.
template<int PLANES, int NREP>
__device__ __forceinline__ void gemm_reg_pipe(
        const unsigned short* __restrict__ a_hi, const unsigned short* __restrict__ a_lo,
        const unsigned short* __restrict__ b_bf,
        char* lds, int m0, int f0, int t, f32x4 (&acc)[NREP][4][4]) {
    const int w = t >> 6, lane = t & 63, l15 = lane & 15, quad = lane >> 4;
    const int mw = (w & 1) * 64, nw = (w >> 1) * 64;
    const int APL = PLANES - 1;           // A planes
    const int NPL = APL + NREP;           // total planes
    const int STAGE = NPL * 4096;         // elements per stage
    const int r = t >> 1;                 // 0..127: row this thread stages
    const int g0 = (t & 1) * 2;           // first of two 16-B col-groups

    uint4 regs[NPL][2];
    auto load_regs = [&](int kt) {
        const int k0 = kt * 32;
        #pragma unroll
        for (int p = 0; p < NPL; p++) {
            const unsigned short* src = (p < APL) ? (p == 0 ? a_hi : a_lo) : b_bf;
            const int row0 = (p < APL) ? m0 : (f0 + (p - APL) * 128);
            const unsigned short* g = src + (size_t)(row0 + r) * DMODEL + k0 + g0 * 8;
            regs[p][0] = *(const uint4*)g;
            regs[p][1] = *(const uint4*)(g + 8);
        }
    };
    auto store_lds = [&](int stage) {
        unsigned short* S = (unsigned short*)lds + stage * STAGE;
        const int s0 = ((g0 ^ swz(r))) * 8;
        const int s1 = (((g0 + 1) ^ swz(r))) * 8;
        #pragma unroll
        for (int p = 0; p < NPL; p++) {
            unsigned short* Sp = S + p * 4096 + r * 32;
            *(uint4*)&Sp[s0] = regs[p][0];
            *(uint4*)&Sp[s1] = regs[p][1];
        }
    };

    load_regs(0);
    store_lds(0);
    for (int kt = 0; kt < 16; kt++) {
        __syncthreads();                  // stage (kt&1) visible to all waves
        if (kt < 15) load_regs(kt + 1);   // issue next tile's global loads NOW
        const unsigned short* S = (const unsigned short*)lds + (kt & 1) * STAGE;
        bf16x8 ah[4], al[4];
        #pragma unroll
        for (int mt = 0; mt < 4; mt++) {
            const int rr = mw + mt * 16 + l15;
            const int off = rr * 32 + (quad ^ swz(rr)) * 8;
            ah[mt] = *(const bf16x8*)&S[off];
            if (APL == 2) al[mt] = *(const bf16x8*)&S[4096 + off];
        }
        #pragma unroll
        for (int nr = 0; nr < NREP; nr++) {
            bf16x8 bb[4];
            #pragma unroll
            for (int nt = 0; nt < 4; nt++) {
                const int rr = nw + nt * 16 + l15;
                bb[nt] = *(const bf16x8*)&S[(APL + nr) * 4096 + rr * 32
                                            + (quad ^ swz(rr)) * 8];
            }
            #pragma unroll
            for (int mt = 0; mt < 4; mt++)
                #pragma unroll
                for (int nt = 0; nt < 4; nt++) {
                    acc[nr][mt][nt] = MFMA16(ah[mt], bb[nt], acc[nr][mt][nt]);
                    if (APL == 2) acc[nr][mt][nt] = MFMA16(al[mt], bb[nt], acc[nr][mt][nt]);
                }
        }
        if (kt < 15) store_lds((kt + 1) & 1);  // vmcnt wait lands here, post-MFMA
    }
    __syncthreads();                      // LDS free for epilogue reuse
}

// ---- qkv pipe: fp32 A -> SINGLE bf16 RTN plane in-register at store time ----
__device__ __forceinline__ void gemm_pipe_qkv(
        const float* __restrict__ x, const unsigned short* __restrict__ b_bf,
        char* lds, int m0, int f0, int t, f32x4 (&acc)[2][4][4]) {
    const int w = t >> 6, lane = t & 63, l15 = lane & 15, quad = lane >> 4;
    const int mw = (w & 1) * 64, nw = (w >> 1) * 64;
    const int STAGE = 3 * 4096;           // planes: 0=A 1=B(f0) 2=B(f0+128)
    const int r = t >> 1;
    const int g0 = (t & 1) * 2;

    float4 af[4];                         // 16 fp32 of A row r, cols k0+g0*8..+16
    uint4 bregs[2][2];
    auto load_regs = [&](int kt) {
        const int k0 = kt * 32;
        const float* gA = x + (size_t)(m0 + r) * DMODEL + k0 + g0 * 8;
        #pragma unroll
        for (int i = 0; i < 4; i++) af[i] = ((const float4*)gA)[i];
        #pragma unroll
        for (int p = 0; p < 2; p++) {
            const unsigned short* g =
                b_bf + (size_t)(f0 + p * 128 + r) * DMODEL + k0 + g0 * 8;
            bregs[p][0] = *(const uint4*)g;
            bregs[p][1] = *(const uint4*)(g + 8);
        }
    };
    auto store_lds = [&](int stage) {
        unsigned short* S = (unsigned short*)lds + stage * STAGE;
        const int s0 = ((g0 ^ swz(r))) * 8;
        const int s1 = (((g0 + 1) ^ swz(r))) * 8;
        // pack 8 floats -> one uint4 of RTN bf16
        auto cvt8 = [](const float4 a, const float4 b) {
            const float f[8] = {a.x, a.y, a.z, a.w, b.x, b.y, b.z, b.w};
            unsigned hw[4];
            #pragma unroll
            for (int j = 0; j < 4; j++)
                hw[j] = (unsigned)bf16_rtn(f[2 * j])
                      | ((unsigned)bf16_rtn(f[2 * j + 1]) << 16);
            return make_uint4(hw[0], hw[1], hw[2], hw[3]);
        };
        unsigned short* Sa = S + r * 32;
        *(uint4*)&Sa[s0] = cvt8(af[0], af[1]);
        *(uint4*)&Sa[s1] = cvt8(af[2], af[3]);
        #pragma unroll
        for (int p = 0; p < 2; p++) {
            unsigned short* Sp = S + (1 + p) * 4096 + r * 32;
            *(uint4*)&Sp[s0] = bregs[p][0];
            *(uint4*)&Sp[s1] = bregs[p][1];
        }
    };

    load_regs(0);
    store_lds(0);
    for (int kt = 0; kt < 16; kt++) {
        __syncthreads();
        if (kt < 15) load_regs(kt + 1);
        const unsigned short* S = (const unsigned short*)lds + (kt & 1) * STAGE;
        bf16x8 ah[4];
        #pragma unroll
        for (int mt = 0; mt < 4; mt++) {
            const int rr = mw + mt * 16 + l15;
            ah[mt] = *(const bf16x8*)&S[rr * 32 + (quad ^ swz(rr)) * 8];
        }
        #pragma unroll
        for (int nr = 0; nr < 2; nr++) {
            bf16x8 bb[4];
            #pragma unroll
            for (int nt = 0; nt < 4; nt++) {
                const int rr = nw + nt * 16 + l15;
                bb[nt] = *(const bf16x8*)&S[(1 + nr) * 4096 + rr * 32
                                            + (quad ^ swz(rr)) * 8];
            }
            #pragma unroll
            for (int mt = 0; mt < 4; mt++)
                #pragma unroll
                for (int nt = 0; nt < 4; nt++)
                    acc[nr][mt][nt] = MFMA16(ah[mt], bb[nt], acc[nr][mt][nt]);
        }
        if (kt < 15) store_lds((kt + 1) & 1);
    }
    __syncthreads();
}

// ---------------- Kernel 1: QKV GEMM + RoPE (128x256 tile, single-plane A) ----
__global__ __launch_bounds__(256, 3) void qkv_mfma_kernel(
        const float* __restrict__ x, const unsigned short* __restrict__ wq_bf,
        unsigned short* __restrict__ q_bf, unsigned short* __restrict__ k_bf,
        unsigned short* __restrict__ v_th) {
    __shared__ __align__(16) char lds[49152 + 4608];   // 2x24KB stages (+T alias) + tables
    unsigned short* T = (unsigned short*)lds;          // 128 x TP transpose buffer
    float* t_cy = (float*)(lds + 49152);               // [4][16]
    float* t_sy = t_cy + 64;
    float* t_cx = t_sy + 64;                           // [32][16]
    float* t_sx = t_cx + 512;

    const int m0 = blockIdx.x * 128;
    const int f0 = blockIdx.y * 256;
    const int t = threadIdx.x;
    const int w = t >> 6, lane = t & 63, l15 = lane & 15, quad = lane >> 4;
    const int mw = (w & 1) * 64, nw = (w >> 1) * 64;
    const int sel = f0 >> 9;                // 0=q,1=k,2=v (same for both subtiles)
    const int bt = m0 >> 10;
    const int n0 = m0 & 1023;

    if (sel != 2) {
        for (int idx = t; idx < 576; idx += 256) {
            if (idx < 64) {
                const int yi = idx >> 4, j = idx & 15;
                const float pos = -1.0f + (float)((n0 >> 5) + yi) * (2.0f / 31.0f);
                float sv, cv; sincosf(pos * freq_of(j), &sv, &cv);
                t_sy[idx] = sv; t_cy[idx] = cv;
            } else {
                const int k2 = idx - 64, xi = k2 >> 4, j = k2 & 15;
                const float pos = -1.0f + (float)xi * (2.0f / 31.0f);
                float sv, cv; sincosf(pos * freq_of(j), &sv, &cv);
                t_sx[k2] = sv; t_cx[k2] = cv;
            }
        }
    }
    __syncthreads();

    f32x4 acc[2][4][4];
    #pragma unroll
    for (int nr = 0; nr < 2; nr++)
        #pragma unroll
        for (int mt = 0; mt < 4; mt++)
            #pragma unroll
            for (int nt = 0; nt < 4; nt++) acc[nr][mt][nt] = (f32x4){0.f, 0.f, 0.f, 0.f};

    gemm_pipe_qkv(x, wq_bf, lds, m0, f0, t, acc);

    #pragma unroll
    for (int nr = 0; nr < 2; nr++) {
        const int fs = f0 + nr * 128;
        if (sel != 2) {
            const float post = (sel == 0) ? QSCALE : 1.0f;
            #pragma unroll
            for (int mt = 0; mt < 4; mt++)
                #pragma unroll
                for (int nt = 0; nt < 4; nt++)
                    #pragma unroll
                    for (int rr = 0; rr < 4; rr++) {
                        const int ml = mw + mt * 16 + quad * 4 + rr;
                        const int dd = (nw + nt * 16 + l15) & 63;
                        const int j0 = (dd & 31) >> 1;
                        float c, s;
                        if (dd < 32) { c = t_cy[(ml >> 5) * 16 + j0]; s = t_sy[(ml >> 5) * 16 + j0]; }
                        else         { c = t_cx[(ml & 31) * 16 + j0]; s = t_sx[(ml & 31) * 16 + j0]; }
                        const float v = acc[nr][mt][nt][rr];
                        const float pv = __shfl_xor(v, 1);
                        acc[nr][mt][nt][rr] =
                            ((l15 & 1) ? (v * c + pv * s) : (v * c - pv * s)) * post;
                    }
        }

        if (sel == 2) {
            #pragma unroll
            for (int mt = 0; mt < 4; mt++)
                #pragma unroll
                for (int nt = 0; nt < 4; nt++) {
                    const int fl = nw + nt * 16 + l15;
                    const int mlb = mw + mt * 16 + quad * 4;
                    ushort4 pk = make_ushort4(
                        bf16_rtn(acc[nr][mt][nt][0]), bf16_rtn(acc[nr][mt][nt][1]),
                        bf16_rtn(acc[nr][mt][nt][2]), bf16_rtn(acc[nr][mt][nt][3]));
                    *(ushort4*)&T[fl * TP + mlb] = pk;
                }
        } else {
            #pragma unroll
            for (int mt = 0; mt < 4; mt++)
                #pragma unroll
                for (int nt = 0; nt < 4; nt++)
                    #pragma unroll
                    for (int rr = 0; rr < 4; rr++) {
                        const int ml = mw + mt * 16 + quad * 4 + rr;
                        const int fl = nw + nt * 16 + l15;
                        T[ml * TP + fl] = bf16_rtn(acc[nr][mt][nt][rr]);
                    }
        }
        __syncthreads();
        if (sel == 2) {
            #pragma unroll
            for (int p = 0; p < 8; p++) {
                const int idx = p * 256 + t;
                const int fl = idx >> 4, g8 = (idx & 15) * 8;
                const int head = ((fs + fl) >> 6) & 7;
                *(uint4*)(v_th + ((size_t)(bt * NH + head) * HD + ((fs + fl) & 63)) * NSEQ
                          + n0 + g8) = *(const uint4*)&T[fl * TP + g8];
            }
        } else {
            unsigned short* dst = (sel == 0) ? q_bf : k_bf;
            #pragma unroll
            for (int p = 0; p < 8; p++) {
                const int idx = p * 256 + t;
                const int ml = idx >> 4, g8 = (idx & 15) * 8;
                const int head = ((fs + g8) >> 6) & 7;
                *(uint4*)(dst + ((size_t)(bt * NH + head) * NSEQ + n0 + ml) * HD
                          + ((fs + g8) & 63)) = *(const uint4*)&T[ml * TP + g8];
            }
        }
        __syncthreads();
    }
}

// ---------------- Kernel 2: flash attention, 8 waves x 32 q-rows, QBLK=256 ----
__global__ __launch_bounds__(512, 2) void attn_kernel(
        const unsigned short* __restrict__ q_bf, const unsigned short* __restrict__ k_bf,
        const unsigned short* __restrict__ v_th,
        unsigned short* __restrict__ o_bf) {
    __shared__ unsigned short Ks[2][64 * KVP];  // K tile [n][d], double-buffered
    __shared__ unsigned short Vs[2][64 * KVP];  // V^T tile [d][n], double-buffered
    __shared__ float Lsh[256];                  // per-row 1/l broadcast

    const int bh = blockIdx.x;     // fastest dim -> XCD = bh & 7 for all 4 qt blocks
    const int qt = blockIdx.y;     // 0..3
    const int t = threadIdx.x;     // 0..511
    const int w = t >> 6;          // 0..7: wave owns 32 q-rows
    const int lane = t & 63;
    const int l31 = lane & 31;
    const int hi = lane >> 5;

    const size_t bh_nd = (size_t)bh * NSEQ * HD;
    const size_t bh_dn = (size_t)bh * HD * NSEQ;

    // Q B-fragments: qrow = qt*256 + w*32 + l31
    bf16x8 qfB[4];
    {
        const size_t rbase =
            bh_nd + (size_t)(qt * 256 + w * 32 + l31) * HD + hi * 8;
        #pragma unroll
        for (int ds = 0; ds < 4; ds++)
            qfB[ds] = *(const bf16x8*)(q_bf + rbase + ds * 16);
    }

    // staging: 512 threads x 1 uint4 each for K and V (64x64 tile each)
    const int sr = t >> 3, soff = (t & 7) * 8;
    uint4 kr, vr;
    auto load_kv = [&](int kt) {
        kr = *(const uint4*)(k_bf + bh_nd + (size_t)(kt * 64 + sr) * HD + soff);
        vr = *(const uint4*)(v_th + bh_dn + (size_t)sr * NSEQ + kt * 64 + soff);
    };
    auto store_kv = [&](int st) {
        *(uint4*)&Ks[st][sr * KVP + soff] = kr;
        *(uint4*)&Vs[st][sr * KVP + soff] = vr;
    };

    f32x16 o_acc[2], zero16;
    float l_sum = 0.f;
    #pragma unroll
    for (int i = 0; i < 16; i++) {
        o_acc[0][i] = 0.f; o_acc[1][i] = 0.f; zero16[i] = 0.f;
    }

    load_kv(0);
    store_kv(0);
    for (int kt = 0; kt < 16; kt++) {
        __syncthreads();                  // stage (kt&1) visible
        if (kt < 15) load_kv(kt + 1);     // prefetch next tile into VGPRs
        const unsigned short* K = Ks[kt & 1];
        const unsigned short* V = Vs[kt & 1];

        #pragma unroll
        for (int nt2 = 0; nt2 < 2; nt2++) {
            bf16x8 kb[4];
            #pragma unroll
            for (int ds = 0; ds < 4; ds++)
                kb[ds] = *(const bf16x8*)&K[(nt2 * 32 + l31) * KVP + ds * 16 + hi * 8];

            // ---- S^T = K · Q^T (zero16-seeded) ----
            __builtin_amdgcn_s_setprio(1);
            f32x16 s = MFMA32(kb[0], qfB[0], zero16);
            #pragma unroll
            for (int ds = 1; ds < 4; ds++) s = MFMA32(kb[ds], qfB[ds], s);
            __builtin_amdgcn_s_setprio(0);

            // ---- p = exp2(s); accumulate l in-lane; pack pairs to bf16 ----
            unsigned wv[8];
            float pp[8];
            #pragma unroll
            for (int i = 0; i < 8; i++) {
                const float p0 = exp2f(s[2 * i]);
                const float p1 = exp2f(s[2 * i + 1]);
                pp[i] = p0 + p1;
                asm("v_cvt_pk_bf16_f32 %0, %1, %2" : "=v"(wv[i]) : "v"(p0), "v"(p1));
            }
            l_sum += ((pp[0] + pp[1]) + (pp[2] + pp[3]))
                   + ((pp[4] + pp[5]) + (pp[6] + pp[7]));

            // ---- exchange halves: vdst.hi <-> vsrc.lo (first operand = lower-k word)
            asm volatile("v_permlane32_swap_b32 %0, %1" : "+v"(wv[0]), "+v"(wv[2]));
            asm volatile("v_permlane32_swap_b32 %0, %1" : "+v"(wv[1]), "+v"(wv[3]));
            asm volatile("v_permlane32_swap_b32 %0, %1" : "+v"(wv[4]), "+v"(wv[6]));
            asm volatile("v_permlane32_swap_b32 %0, %1" : "+v"(wv[5]), "+v"(wv[7]));

            // ---- O += P·V (P entirely in registers) ----
            __builtin_amdgcn_s_setprio(1);
            #pragma unroll
            for (int k2 = 0; k2 < 2; k2++) {
                const u32x4 paw = {wv[k2 * 4 + 0], wv[k2 * 4 + 1],
                                   wv[k2 * 4 + 2], wv[k2 * 4 + 3]};
                const bf16x8 pa = __builtin_bit_cast(bf16x8, paw);
                #pragma unroll
                for (int dt = 0; dt < 2; dt++) {
                    const bf16x8 vb = *(const bf16x8*)&V[(dt * 32 + l31) * KVP
                                         + (nt2 * 2 + k2) * 16 + hi * 8];
                    o_acc[dt] = MFMA32(pa, vb, o_acc[dt]);
                }
            }
            __builtin_amdgcn_s_setprio(0);
        }
        if (kt < 15) store_kv((kt + 1) & 1);  // vmcnt wait lands post-MFMA
    }

    // ---- combine row-sum halves; broadcast 1/l via LDS (intra-wave rows) ----
    l_sum += __shfl_xor(l_sum, 32);
    const float inv = 1.0f / l_sum;
    if (hi == 0) Lsh[w * 32 + l31] = inv;
    __syncthreads();                       // Lsh visible + Ks/Vs reads done

    // ---- epilogue: LDS bounce -> full-128B-line uint4 stores ----
    unsigned short* Osh = &Ks[0][0];       // 256 rows x KVP pitch = 18432 els (Ks+Vs)
    #pragma unroll
    for (int r = 0; r < 16; r++) {
        const int row32 = (r & 3) + 8 * (r >> 2) + 4 * hi;
        const float invr = Lsh[w * 32 + row32];
        const int row = w * 32 + row32;
        #pragma unroll
        for (int dt = 0; dt < 2; dt++)
            Osh[row * KVP + dt * 32 + l31] = bf16_rtn(o_acc[dt][r] * invr);
    }
    __syncthreads();
    const int btq = bh >> 3, head = bh & 7;
    #pragma unroll
    for (int p = 0; p < 4; p++) {
        const int idx = p * 512 + t;
        const int row = idx >> 3, g8 = (idx & 7) * 8;
        *(uint4*)(o_bf + ((size_t)(btq * NSEQ + qt * 256 + row)) * DMODEL
                  + head * HD + g8) = *(const uint4*)&Osh[row * KVP + g8];
    }
}

// ---------------- Kernel 3: output projection (128x256, NREP=2, pipelined) ----------------
__global__ __launch_bounds__(256, 2) void proj_mfma_kernel(
        const unsigned short* __restrict__ o_bf,
        const unsigned short* __restrict__ wo_bf,
        const float* __restrict__ b_out, float* __restrict__ out) {
    __shared__ __align__(16) char lds[49152];   // 2 x 24KB stages (3 planes)

    const int m0 = blockIdx.x * 128;
    const int f0 = blockIdx.y * 256;
    const int t = threadIdx.x;
    const int w = t >> 6, lane = t & 63, l15 = lane & 15, quad = lane >> 4;
    const int mw = (w & 1) * 64, nw = (w >> 1) * 64;

    f32x4 acc[2][4][4];
    #pragma unroll
    for (int nr = 0; nr < 2; nr++)
        #pragma unroll
        for (int mt = 0; mt < 4; mt++)
            #pragma unroll
            for (int nt = 0; nt < 4; nt++) acc[nr][mt][nt] = (f32x4){0.f, 0.f, 0.f, 0.f};

    gemm_reg_pipe<2, 2>(o_bf, o_bf, wo_bf, lds, m0, f0, t, acc);

    #pragma unroll
    for (int nr = 0; nr < 2; nr++) {
        const int fs = f0 + nr * 128;
        float bias_v[4];
        #pragma unroll
        for (int nt = 0; nt < 4; nt++) bias_v[nt] = b_out[fs + nw + nt * 16 + l15];
        #pragma unroll
        for (int mt = 0; mt < 4; mt++)
            #pragma unroll
            for (int nt = 0; nt < 4; nt++)
                #pragma unroll
                for (int rr = 0; rr < 4; rr++) {
                    const int m = m0 + mw + mt * 16 + quad * 4 + rr;
                    out[(size_t)m * DMODEL + fs + nw + nt * 16 + l15] =
                        acc[nr][mt][nt][rr] + bias_v[nt];
                }
    }
}

extern "C" void kernel_launch(void* const* d_in, const int* in_sizes, int n_in,
                              void* d_out, int out_size, void* d_ws, size_t ws_size,
                              hipStream_t stream) {
    const float* x  = (const float*)d_in[0];
    const float* wq = (const float*)d_in[1];
    const float* wo = (const float*)d_in[2];
    const float* bo = (const float*)d_in[3];
    float* out = (float*)d_out;

    const size_t per = (size_t)BH * NSEQ * HD;   // 8,388,608 elements
    unsigned short* o_bf = (unsigned short*)d_ws;
    unsigned short* q_bf = o_bf + per;
    unsigned short* k_bf = q_bf + per;
    unsigned short* v_th = k_bf + per;
    unsigned short* wq_bf = v_th + per;                   // 786,432 els
    unsigned short* wo_bf = wq_bf + (size_t)F3 * DMODEL;  // 262,144 els (~66 MiB total)

    cvt2_kernel<<<dim3((F3 * DMODEL + DMODEL * DMODEL) / 1024), 256, 0, stream>>>(
        wq, wq_bf, wo, wo_bf);
    qkv_mfma_kernel<<<dim3(NTOK / 128, F3 / 256), 256, 0, stream>>>(
        x, wq_bf, q_bf, k_bf, v_th);
    attn_kernel<<<dim3(BH, 4), 512, 0, stream>>>(
        q_bf, k_bf, v_th, o_bf);
    proj_mfma_kernel<<<dim3(NTOK / 128, DMODEL / 256), 256, 0, stream>>>(
        o_bf, wo_bf, bo, out);
}